// Round 1
// baseline (5219.534 us; speedup 1.0000x reference)
//
#include <hip/hip_runtime.h>
#include <cstddef>
#include <cstdint>

#define NSG   8
#define NPAIR 28
#define NBLK  36
#define NPT   1024
#define DIM   256
#define NROW  8192
#define LOG_N 6.9314718055994531f

// triu_indices(8,1) pairs, then 8 self pairs
__constant__ int c_pa[NBLK] = {0,0,0,0,0,0,0,1,1,1,1,1,1,2,2,2,2,2,3,3,3,3,4,4,4,5,5,6, 0,1,2,3,4,5,6,7};
__constant__ int c_pb[NBLK] = {1,2,3,4,5,6,7,2,3,4,5,6,7,3,4,5,6,7,4,5,6,7,5,6,7,6,7,7, 0,1,2,3,4,5,6,7};

__device__ __forceinline__ float wredMax(float v) {
#pragma unroll
  for (int o = 32; o > 0; o >>= 1) v = fmaxf(v, __shfl_xor(v, o, 64));
  return v;
}
__device__ __forceinline__ float wredSum(float v) {
#pragma unroll
  for (int o = 32; o > 0; o >>= 1) v += __shfl_xor(v, o, 64);
  return v;
}

// ---- phase 0: grouping ----
__global__ void build_idx(const int* __restrict__ sg, int* __restrict__ idx, int* __restrict__ cnt) {
  int i = blockIdx.x * 256 + threadIdx.x;
  if (i >= NROW) return;
  int s = sg[i];
  int r = atomicAdd(&cnt[s], 1);
  idx[s * NPT + r] = i;
}

__global__ void gather_rows(const float* __restrict__ feat, const int* __restrict__ idx,
                            float* __restrict__ G, float* __restrict__ sq) {
  int row = blockIdx.x;
  int src = idx[row];
  float v = feat[(size_t)src * DIM + threadIdx.x];
  G[(size_t)row * DIM + threadIdx.x] = v;
  float p = wredSum(v * v);
  __shared__ float ws[4];
  if ((threadIdx.x & 63) == 0) ws[threadIdx.x >> 6] = p;
  __syncthreads();
  if (threadIdx.x == 0) sq[row] = 0.5f * (ws[0] + ws[1] + ws[2] + ws[3]);
}

// ---- phase 1: cost matrices. 36 blocks of 1024x1024, tile 128x128 per workgroup ----
__global__ __launch_bounds__(256) void cost_gemm(const float* __restrict__ G,
                                                 const float* __restrict__ sq,
                                                 float* __restrict__ Cxy,
                                                 float* __restrict__ Cxx) {
  __shared__ float As[8][128];
  __shared__ float Bt[8][128];
  int blk = blockIdx.x;
  int b = blk >> 6, t = blk & 63;
  int sa = c_pa[b], sb = c_pb[b];
  int i0 = (t >> 3) << 7, j0 = (t & 7) << 7;
  const float* Arows = G + (size_t)(sa * NPT + i0) * DIM;
  const float* Brows = G + (size_t)(sb * NPT + j0) * DIM;
  int tid = threadIdx.x;
  int ty = tid >> 4, tx = tid & 15;
  float acc[8][8];
#pragma unroll
  for (int r = 0; r < 8; r++)
#pragma unroll
    for (int q = 0; q < 8; q++) acc[r][q] = 0.f;

  int lrow = tid >> 1, lk4 = (tid & 1) << 2;
  for (int k0 = 0; k0 < DIM; k0 += 8) {
    __syncthreads();
    float4 av = *(const float4*)(Arows + (size_t)lrow * DIM + k0 + lk4);
    float4 bv = *(const float4*)(Brows + (size_t)lrow * DIM + k0 + lk4);
    As[lk4 + 0][lrow] = av.x; As[lk4 + 1][lrow] = av.y; As[lk4 + 2][lrow] = av.z; As[lk4 + 3][lrow] = av.w;
    Bt[lk4 + 0][lrow] = bv.x; Bt[lk4 + 1][lrow] = bv.y; Bt[lk4 + 2][lrow] = bv.z; Bt[lk4 + 3][lrow] = bv.w;
    __syncthreads();
#pragma unroll
    for (int kk = 0; kk < 8; kk++) {
      float4 a0 = *(const float4*)&As[kk][ty << 3];
      float4 a1 = *(const float4*)&As[kk][(ty << 3) + 4];
      float4 b0 = *(const float4*)&Bt[kk][tx << 3];
      float4 b1 = *(const float4*)&Bt[kk][(tx << 3) + 4];
      float ar[8] = {a0.x, a0.y, a0.z, a0.w, a1.x, a1.y, a1.z, a1.w};
      float br[8] = {b0.x, b0.y, b0.z, b0.w, b1.x, b1.y, b1.z, b1.w};
#pragma unroll
      for (int r = 0; r < 8; r++)
#pragma unroll
        for (int q = 0; q < 8; q++) acc[r][q] = fmaf(ar[r], br[q], acc[r][q]);
    }
  }
  float* dst = (b < NPAIR) ? (Cxy + ((size_t)b << 20)) : (Cxx + ((size_t)(b - NPAIR) << 20));
  float sqa[8], sqb[8];
#pragma unroll
  for (int r = 0; r < 8; r++) sqa[r] = sq[sa * NPT + i0 + (ty << 3) + r];
#pragma unroll
  for (int q = 0; q < 8; q++) sqb[q] = sq[sb * NPT + j0 + (tx << 3) + q];
#pragma unroll
  for (int r = 0; r < 8; r++) {
    float* drow = dst + (size_t)(i0 + (ty << 3) + r) * NPT + j0 + (tx << 3);
    float4 o0, o1;
    o0.x = fmaxf(sqa[r] + sqb[0] - acc[r][0], 0.f);
    o0.y = fmaxf(sqa[r] + sqb[1] - acc[r][1], 0.f);
    o0.z = fmaxf(sqa[r] + sqb[2] - acc[r][2], 0.f);
    o0.w = fmaxf(sqa[r] + sqb[3] - acc[r][3], 0.f);
    o1.x = fmaxf(sqa[r] + sqb[4] - acc[r][4], 0.f);
    o1.y = fmaxf(sqa[r] + sqb[5] - acc[r][5], 0.f);
    o1.z = fmaxf(sqa[r] + sqb[6] - acc[r][6], 0.f);
    o1.w = fmaxf(sqa[r] + sqb[7] - acc[r][7], 0.f);
    ((float4*)drow)[0] = o0;
    ((float4*)drow)[1] = o1;
  }
}

// ---- phase 2: Sinkhorn step pieces ----

// rows: out[i] = cs*h[i] + cm * (-(m + eps*(log(sum)-log n))) over row LSE of (h[j]-C[i][j])/eps
__device__ __forceinline__ void row_softmin(const float* __restrict__ C, const float* __restrict__ h,
                                            float* __restrict__ out, int p, int rowBlk,
                                            float eps, float cs, float cm, float* lds) {
  const float* Cp = C + ((size_t)p << 20);
  const float* hp = h + p * NPT;
  for (int t = threadIdx.x; t < NPT; t += 256) lds[t] = hp[t];
  __syncthreads();
  int wave = threadIdx.x >> 6, lane = threadIdx.x & 63;
  int i = (rowBlk << 2) + wave;
  const float4* Crow = (const float4*)(Cp + ((size_t)i << 10));
  const float4* h4 = (const float4*)lds;
  float4 a[4];
  float m = -3.4e38f;
#pragma unroll
  for (int c = 0; c < 4; c++) {
    float4 cv = Crow[(c << 6) + lane];
    float4 hv = h4[(c << 6) + lane];
    a[c].x = hv.x - cv.x; a[c].y = hv.y - cv.y; a[c].z = hv.z - cv.z; a[c].w = hv.w - cv.w;
    m = fmaxf(m, fmaxf(fmaxf(a[c].x, a[c].y), fmaxf(a[c].z, a[c].w)));
  }
  m = wredMax(m);
  float ie = 1.0f / eps;
  float ssum = 0.f;
#pragma unroll
  for (int c = 0; c < 4; c++) {
    ssum += __expf((a[c].x - m) * ie) + __expf((a[c].y - m) * ie) +
            __expf((a[c].z - m) * ie) + __expf((a[c].w - m) * ie);
  }
  ssum = wredSum(ssum);
  if (lane == 0) {
    float sm = -(m + eps * (__logf(ssum) - LOG_N));
    out[p * NPT + i] = cs * lds[i] + cm * sm;
  }
}

// columns: partial online LSE over a 128-row chunk; thread = one column
__device__ __forceinline__ void col_partials(const float* __restrict__ Cxy, const float* __restrict__ f,
                                             float2* __restrict__ part, int idx, float eps, float* lds) {
  int p = idx >> 5;
  int rem = idx & 31;
  int cc = rem >> 3;
  int rc = rem & 7;
  const float* Cp = Cxy + ((size_t)p << 20);
  int j = (cc << 8) + threadIdx.x;
  if (threadIdx.x < 128) lds[threadIdx.x] = f[p * NPT + (rc << 7) + threadIdx.x];
  __syncthreads();
  float ie = 1.0f / eps;
  float m = -3.4e38f, l = 0.f;
  const float* Cbase = Cp + ((size_t)(rc << 7) << 10) + j;
  for (int c = 0; c < 16; c++) {
    float a[8];
#pragma unroll
    for (int r = 0; r < 8; r++)
      a[r] = lds[(c << 3) + r] - Cbase[((size_t)((c << 3) + r)) << 10];
    float cmx = a[0];
#pragma unroll
    for (int r = 1; r < 8; r++) cmx = fmaxf(cmx, a[r]);
    float mn = fmaxf(m, cmx);
    l *= __expf((m - mn) * ie);
#pragma unroll
    for (int r = 0; r < 8; r++) l += __expf((a[r] - mn) * ie);
    m = mn;
  }
  part[(size_t)((p << 3) + rc) * NPT + j] = make_float2(m, l);
}

#define NA 7168
#define NBB 2048
#define NC 896

__global__ __launch_bounds__(256) void sink_step(const float* __restrict__ Cxy, const float* __restrict__ Cxx,
                                                 const float* __restrict__ f_cur, const float* __restrict__ g_cur,
                                                 const float* __restrict__ s_cur,
                                                 float* __restrict__ f_nxt, float* __restrict__ s_nxt,
                                                 float2* __restrict__ part,
                                                 float eps, float csS, float cmS) {
  __shared__ __align__(16) float lds[NPT];
  int b = blockIdx.x;
  if (b < NA) {
    row_softmin(Cxy, g_cur, f_nxt, b >> 8, b & 255, eps, 0.f, 1.f, lds);
  } else if (b < NA + NBB) {
    int bb = b - NA;
    row_softmin(Cxx, s_cur, s_nxt, bb >> 8, bb & 255, eps, csS, cmS, lds);
  } else {
    col_partials(Cxy, f_cur, part, b - (NA + NBB), eps, lds);
  }
}

__global__ void combine_g(const float2* __restrict__ part, float* __restrict__ g, float eps) {
  int jg = blockIdx.x * 256 + threadIdx.x;  // 28*1024 total
  int p = jg >> 10, j = jg & 1023;
  float ie = 1.0f / eps;
  float2 v[8];
  float m = -3.4e38f;
#pragma unroll
  for (int r = 0; r < 8; r++) {
    v[r] = part[(size_t)((p << 3) + r) * NPT + j];
    m = fmaxf(m, v[r].x);
  }
  float s = 0.f;
#pragma unroll
  for (int r = 0; r < 8; r++) s += v[r].y * __expf((v[r].x - m) * ie);
  g[jg] = -(m + eps * (__logf(s) - LOG_N));
}

// ---- phase 3: losses ----
__global__ void loss_pairs(const float* __restrict__ ff, const float* __restrict__ gf,
                           const float* __restrict__ sf, float* __restrict__ out) {
  int p = blockIdx.x;
  int si = c_pa[p], sj = c_pb[p];
  float acc = 0.f;
  for (int t = threadIdx.x; t < NPT; t += 256)
    acc += (ff[p * NPT + t] - sf[si * NPT + t]) + (gf[p * NPT + t] - sf[sj * NPT + t]);
  acc = wredSum(acc);
  __shared__ float ws[4];
  if ((threadIdx.x & 63) == 0) ws[threadIdx.x >> 6] = acc;
  __syncthreads();
  if (threadIdx.x == 0) out[1 + p] = (ws[0] + ws[1] + ws[2] + ws[3]) * (1.0f / NPT);
}

__global__ void loss_total(float* __restrict__ out) {
  int t = threadIdx.x;
  float x = (t < NPAIR) ? out[1 + t] : 0.f;
  x = wredSum(x);
  if (t == 0) out[0] = x / (float)NPAIR;
}

extern "C" void kernel_launch(void* const* d_in, const int* in_sizes, int n_in,
                              void* d_out, int out_size, void* d_ws, size_t ws_size,
                              hipStream_t stream) {
  const float* feat = (const float*)d_in[0];
  const int* sg = (const int*)d_in[1];
  float* out = (float*)d_out;
  char* ws = (char*)d_ws;

  // workspace layout (bytes)
  size_t oCxy = 0;                                    // 28*1024*1024*4 = 117440512
  size_t oCxx = oCxy + (size_t)NPAIR * NPT * NPT * 4; // 150994944
  size_t oG   = oCxx + (size_t)NSG * NPT * NPT * 4;   // +33554432
  size_t oSq  = oG + (size_t)NROW * DIM * 4;          // +8388608
  size_t oIdx = oSq + (size_t)NROW * 4;
  size_t oCnt = oIdx + (size_t)NROW * 4;
  size_t oPot0 = oCnt + 256;
  size_t oPot1 = oPot0 + (size_t)(NPAIR + NPAIR + NSG) * NPT * 4;
  size_t oPart = oPot1 + (size_t)(NPAIR + NPAIR + NSG) * NPT * 4;

  float* Cxy = (float*)(ws + oCxy);
  float* Cxx = (float*)(ws + oCxx);
  float* G   = (float*)(ws + oG);
  float* sq  = (float*)(ws + oSq);
  int* idx   = (int*)(ws + oIdx);
  int* cnt   = (int*)(ws + oCnt);
  float* f[2], *g[2], *s[2];
  f[0] = (float*)(ws + oPot0);
  g[0] = f[0] + NPAIR * NPT;
  s[0] = g[0] + NPAIR * NPT;
  f[1] = (float*)(ws + oPot1);
  g[1] = f[1] + NPAIR * NPT;
  s[1] = g[1] + NPAIR * NPT;
  float2* part = (float2*)(ws + oPart);

  hipMemsetAsync(cnt, 0, 256, stream);
  hipMemsetAsync(f[0], 0, (size_t)(NPAIR + NPAIR + NSG) * NPT * 4, stream);  // f0,g0,s0 = 0

  build_idx<<<NROW / 256, 256, 0, stream>>>(sg, idx, cnt);
  gather_rows<<<NROW, 256, 0, stream>>>(feat, idx, G, sq);
  cost_gemm<<<NBLK * 64, 256, 0, stream>>>(G, sq, Cxy, Cxx);

  // epsilon schedule (mirrors reference host-side logic)
  float sched[256];
  int ns = 0;
  {
    double eps = 256.0;
    const double ratio = 0.9 * 0.9;
    const double tgt = 1e-4 * 1e-4;
    while (eps > tgt) { sched[ns++] = (float)eps; eps *= ratio; }
    sched[ns++] = (float)tgt;
  }
  float epsT = sched[ns - 1];

  int cur = 0;
  for (int k = 0; k < ns; k++) {
    float e = sched[k];
    sink_step<<<NA + NBB + NC, 256, 0, stream>>>(Cxy, Cxx, f[cur], g[cur], s[cur],
                                                 f[1 - cur], s[1 - cur], part, e, 0.5f, 0.5f);
    combine_g<<<NPAIR * NPT / 256, 256, 0, stream>>>(part, g[1 - cur], e);
    cur ^= 1;
  }
  // final extrapolation at eps_target: f_fin, g_fin, s_fin (no blend on s)
  sink_step<<<NA + NBB + NC, 256, 0, stream>>>(Cxy, Cxx, f[cur], g[cur], s[cur],
                                               f[1 - cur], s[1 - cur], part, epsT, 0.0f, 1.0f);
  combine_g<<<NPAIR * NPT / 256, 256, 0, stream>>>(part, g[1 - cur], epsT);

  loss_pairs<<<NPAIR, 256, 0, stream>>>(f[1 - cur], g[1 - cur], s[1 - cur], out);
  loss_total<<<1, 64, 0, stream>>>(out);
}

// Round 2
// 4417.789 us; speedup vs baseline: 1.1815x; 1.1815x over previous
//
#include <hip/hip_runtime.h>
#include <hip/hip_fp16.h>
#include <cstddef>
#include <cstdint>

#define NSG   8
#define NPAIR 28
#define NBLK  36
#define NPT   1024
#define DIM   256
#define NROW  8192
#define NCH   16                 // column-partial chunks (64 rows each)
#define FBLK  (NPAIR * NCH)      // 448 fused f/g blocks
#define SBLK  (NSG * NCH)        // 128 s blocks
#define LOG_N 6.9314718055994531f

// triu_indices(8,1) pairs, then 8 self pairs
__constant__ int c_pa[NBLK] = {0,0,0,0,0,0,0,1,1,1,1,1,1,2,2,2,2,2,3,3,3,3,4,4,4,5,5,6, 0,1,2,3,4,5,6,7};
__constant__ int c_pb[NBLK] = {1,2,3,4,5,6,7,2,3,4,5,6,7,3,4,5,6,7,4,5,6,7,5,6,7,6,7,7, 0,1,2,3,4,5,6,7};

__device__ __forceinline__ float wredMax(float v) {
#pragma unroll
  for (int o = 32; o > 0; o >>= 1) v = fmaxf(v, __shfl_xor(v, o, 64));
  return v;
}
__device__ __forceinline__ float wredSum(float v) {
#pragma unroll
  for (int o = 32; o > 0; o >>= 1) v += __shfl_xor(v, o, 64);
  return v;
}

__device__ __forceinline__ float4 ld4h(const __half* pp) {
  union { uint2 u; __half2 h[2]; } t;
  t.u = *(const uint2*)pp;
  float2 lo = __half22float2(t.h[0]);
  float2 hi = __half22float2(t.h[1]);
  return make_float4(lo.x, lo.y, hi.x, hi.y);
}

// ---- phase 0: grouping ----
__global__ void build_idx(const int* __restrict__ sg, int* __restrict__ idx, int* __restrict__ cnt) {
  int i = blockIdx.x * 256 + threadIdx.x;
  if (i >= NROW) return;
  int s = sg[i];
  int r = atomicAdd(&cnt[s], 1);
  idx[s * NPT + r] = i;
}

__global__ void gather_rows(const float* __restrict__ feat, const int* __restrict__ idx,
                            float* __restrict__ G, float* __restrict__ sq) {
  int row = blockIdx.x;
  int src = idx[row];
  float v = feat[(size_t)src * DIM + threadIdx.x];
  G[(size_t)row * DIM + threadIdx.x] = v;
  float p = wredSum(v * v);
  __shared__ float ws[4];
  if ((threadIdx.x & 63) == 0) ws[threadIdx.x >> 6] = p;
  __syncthreads();
  if (threadIdx.x == 0) sq[row] = 0.5f * (ws[0] + ws[1] + ws[2] + ws[3]);
}

// ---- phase 1: cost matrices (fp16 output). 36 blocks of 1024x1024, tile 128x128 ----
__global__ __launch_bounds__(256) void cost_gemm(const float* __restrict__ G,
                                                 const float* __restrict__ sq,
                                                 __half* __restrict__ Cxy,
                                                 __half* __restrict__ Cxx) {
  __shared__ float As[8][128];
  __shared__ float Bt[8][128];
  int blk = blockIdx.x;
  int b = blk >> 6, t = blk & 63;
  int sa = c_pa[b], sb = c_pb[b];
  int i0 = (t >> 3) << 7, j0 = (t & 7) << 7;
  const float* Arows = G + (size_t)(sa * NPT + i0) * DIM;
  const float* Brows = G + (size_t)(sb * NPT + j0) * DIM;
  int tid = threadIdx.x;
  int ty = tid >> 4, tx = tid & 15;
  float acc[8][8];
#pragma unroll
  for (int r = 0; r < 8; r++)
#pragma unroll
    for (int q = 0; q < 8; q++) acc[r][q] = 0.f;

  int lrow = tid >> 1, lk4 = (tid & 1) << 2;
  for (int k0 = 0; k0 < DIM; k0 += 8) {
    __syncthreads();
    float4 av = *(const float4*)(Arows + (size_t)lrow * DIM + k0 + lk4);
    float4 bv = *(const float4*)(Brows + (size_t)lrow * DIM + k0 + lk4);
    As[lk4 + 0][lrow] = av.x; As[lk4 + 1][lrow] = av.y; As[lk4 + 2][lrow] = av.z; As[lk4 + 3][lrow] = av.w;
    Bt[lk4 + 0][lrow] = bv.x; Bt[lk4 + 1][lrow] = bv.y; Bt[lk4 + 2][lrow] = bv.z; Bt[lk4 + 3][lrow] = bv.w;
    __syncthreads();
#pragma unroll
    for (int kk = 0; kk < 8; kk++) {
      float4 a0 = *(const float4*)&As[kk][ty << 3];
      float4 a1 = *(const float4*)&As[kk][(ty << 3) + 4];
      float4 b0 = *(const float4*)&Bt[kk][tx << 3];
      float4 b1 = *(const float4*)&Bt[kk][(tx << 3) + 4];
      float ar[8] = {a0.x, a0.y, a0.z, a0.w, a1.x, a1.y, a1.z, a1.w};
      float br[8] = {b0.x, b0.y, b0.z, b0.w, b1.x, b1.y, b1.z, b1.w};
#pragma unroll
      for (int r = 0; r < 8; r++)
#pragma unroll
        for (int q = 0; q < 8; q++) acc[r][q] = fmaf(ar[r], br[q], acc[r][q]);
    }
  }
  __half* dst = (b < NPAIR) ? (Cxy + ((size_t)b << 20)) : (Cxx + ((size_t)(b - NPAIR) << 20));
  float sqa[8], sqb[8];
#pragma unroll
  for (int r = 0; r < 8; r++) sqa[r] = sq[sa * NPT + i0 + (ty << 3) + r];
#pragma unroll
  for (int q = 0; q < 8; q++) sqb[q] = sq[sb * NPT + j0 + (tx << 3) + q];
#pragma unroll
  for (int r = 0; r < 8; r++) {
    __half* drow = dst + (size_t)(i0 + (ty << 3) + r) * NPT + j0 + (tx << 3);
    union { float4 f4; __half h[8]; } o;
#pragma unroll
    for (int q = 0; q < 8; q++)
      o.h[q] = __float2half_rn(fmaxf(sqa[r] + sqb[q] - acc[r][q], 0.f));
    *(float4*)drow = o.f4;
  }
}

// ---- phase 2: one fused Sinkhorn step ----
// f-block (pair p, 64-row chunk): combine g from part_cur, row-softmin -> f_nxt,
// column online-LSE partials over its rows -> part_nxt.
// s-block (subgroup p, 64-row chunk): row-softmin with blend -> s_nxt.
__global__ __launch_bounds__(256) void sink_fused(
    const __half* __restrict__ Cxy, const __half* __restrict__ Cxx,
    const float* __restrict__ f_cur, const float* __restrict__ s_cur,
    const float2* __restrict__ part_cur,
    float* __restrict__ f_nxt, float* __restrict__ s_nxt,
    float2* __restrict__ part_nxt,
    float eps_prev, float eps, float csS, float cmS) {
  __shared__ __align__(16) __half tile[8][NPT];   // 16 KB strip
  __shared__ __align__(16) float hvec[NPT];       // g (combined) or s_cur
  __shared__ float fv[64];
  const int tid = threadIdx.x;
  const int b = blockIdx.x;
  const bool isF = (b < FBLK);
  const float ie = 1.0f / eps;
  int p, chunk;
  const __half* Cbase;
  if (isF) {
    p = b >> 4; chunk = b & 15;
    const float iep = 1.0f / eps_prev;
    const float2* pp = part_cur + (size_t)p * (NCH * NPT);
    const int j4 = tid << 2;
    float M[4], L[4];
#pragma unroll
    for (int q = 0; q < 4; q++) { M[q] = -3.4e38f; L[q] = 0.f; }
    for (int c = 0; c < NCH; c++) {
      const float4* q4 = (const float4*)(pp + (size_t)c * NPT + j4);
      float4 A = q4[0], B = q4[1];
      float mx[4] = {A.x, A.z, B.x, B.z};
      float lx[4] = {A.y, A.w, B.y, B.w};
#pragma unroll
      for (int q = 0; q < 4; q++) {
        float nm = fmaxf(M[q], mx[q]);
        L[q] = L[q] * __expf((M[q] - nm) * iep) + lx[q] * __expf((mx[q] - nm) * iep);
        M[q] = nm;
      }
    }
#pragma unroll
    for (int q = 0; q < 4; q++)
      hvec[j4 + q] = -(M[q] + eps_prev * (__logf(L[q]) - LOG_N));
    if (tid < 64) fv[tid] = f_cur[p * NPT + (chunk << 6) + tid];
    Cbase = Cxy + ((size_t)p << 20) + ((size_t)(chunk << 6) << 10);
  } else {
    const int bb = b - FBLK;
    p = bb >> 4; chunk = bb & 15;
    for (int t = tid; t < NPT; t += 256) hvec[t] = s_cur[p * NPT + t];
    Cbase = Cxx + ((size_t)p << 20) + ((size_t)(chunk << 6) << 10);
  }
  __syncthreads();

  const int wave = tid >> 6, lane = tid & 63;
  float CM[4], CL[4];
#pragma unroll
  for (int q = 0; q < 4; q++) { CM[q] = -3.4e38f; CL[q] = 0.f; }

  for (int st = 0; st < 8; st++) {
    // stage 8 rows x 1024 cols (fp16) into LDS, coalesced float4 copy
    const float4* gsrc = (const float4*)(Cbase + ((size_t)(st << 3) << 10));
    float4* ldst = (float4*)&tile[0][0];
#pragma unroll
    for (int k = 0; k < 4; k++) ldst[tid + (k << 8)] = gsrc[tid + (k << 8)];
    __syncthreads();

    // row phase: wave w handles rows w and w+4
#pragma unroll
    for (int rr = 0; rr < 2; rr++) {
      const int row = wave + (rr << 2);
      float a[16];
      float m = -3.4e38f;
#pragma unroll
      for (int c = 0; c < 4; c++) {
        const int col = (c << 8) + (lane << 2);
        float4 cv = ld4h(&tile[row][col]);
        float4 hv = *(const float4*)&hvec[col];
        a[4 * c + 0] = hv.x - cv.x; a[4 * c + 1] = hv.y - cv.y;
        a[4 * c + 2] = hv.z - cv.z; a[4 * c + 3] = hv.w - cv.w;
        m = fmaxf(m, fmaxf(fmaxf(a[4 * c + 0], a[4 * c + 1]), fmaxf(a[4 * c + 2], a[4 * c + 3])));
      }
      m = wredMax(m);
      float ssum = 0.f;
#pragma unroll
      for (int i = 0; i < 16; i++) ssum += __expf((a[i] - m) * ie);
      ssum = wredSum(ssum);
      if (lane == 0) {
        const float sm = -(m + eps * (__logf(ssum) - LOG_N));
        const int gr = (chunk << 6) + (st << 3) + row;
        if (isF) f_nxt[p * NPT + gr] = sm;
        else s_nxt[p * NPT + gr] = csS * hvec[gr] + cmS * sm;
      }
    }

    // col phase (f blocks only): thread owns 4 consecutive cols
    if (isF) {
      const int j4 = tid << 2;
      float av[4][8];
#pragma unroll
      for (int r = 0; r < 8; r++) {
        float4 cv = ld4h(&tile[r][j4]);
        const float fr = fv[(st << 3) + r];
        av[0][r] = fr - cv.x; av[1][r] = fr - cv.y;
        av[2][r] = fr - cv.z; av[3][r] = fr - cv.w;
      }
#pragma unroll
      for (int q = 0; q < 4; q++) {
        float cmx = av[q][0];
#pragma unroll
        for (int r = 1; r < 8; r++) cmx = fmaxf(cmx, av[q][r]);
        const float nm = fmaxf(CM[q], cmx);
        float l = CL[q] * __expf((CM[q] - nm) * ie);
#pragma unroll
        for (int r = 0; r < 8; r++) l += __expf((av[q][r] - nm) * ie);
        CM[q] = nm; CL[q] = l;
      }
    }
    __syncthreads();
  }
  if (isF) {
    float2* pdst = part_nxt + ((size_t)p * NCH + chunk) * NPT + (tid << 2);
#pragma unroll
    for (int q = 0; q < 4; q++) pdst[q] = make_float2(CM[q], CL[q]);
  }
}

// part_0 encodes g=0 for any eps: m=0, l = n/NCH  (sum l = n -> log(n)-log(n)=0)
__global__ void part_init(float2* __restrict__ part) {
  int i = blockIdx.x * 256 + threadIdx.x;
  part[i] = make_float2(0.f, (float)(NPT / NCH));
}

// ---- phase 3: losses (combines g_fin from final partials itself) ----
__global__ void loss_pairs(const float* __restrict__ ff, const float* __restrict__ sf,
                           const float2* __restrict__ part, float* __restrict__ out, float epsT) {
  const int pb = blockIdx.x;
  const int si = c_pa[pb], sj = c_pb[pb];
  const float iep = 1.0f / epsT;
  const int j4 = threadIdx.x << 2;
  const float2* pp = part + (size_t)pb * (NCH * NPT);
  float M[4], L[4];
#pragma unroll
  for (int q = 0; q < 4; q++) { M[q] = -3.4e38f; L[q] = 0.f; }
  for (int c = 0; c < NCH; c++) {
    const float4* q4 = (const float4*)(pp + (size_t)c * NPT + j4);
    float4 A = q4[0], B = q4[1];
    float mx[4] = {A.x, A.z, B.x, B.z};
    float lx[4] = {A.y, A.w, B.y, B.w};
#pragma unroll
    for (int q = 0; q < 4; q++) {
      float nm = fmaxf(M[q], mx[q]);
      L[q] = L[q] * __expf((M[q] - nm) * iep) + lx[q] * __expf((mx[q] - nm) * iep);
      M[q] = nm;
    }
  }
  float acc = 0.f;
#pragma unroll
  for (int q = 0; q < 4; q++) {
    float g = -(M[q] + epsT * (__logf(L[q]) - LOG_N));
    acc += g - sf[sj * NPT + j4 + q];
  }
  for (int t = threadIdx.x; t < NPT; t += 256) acc += ff[pb * NPT + t] - sf[si * NPT + t];
  acc = wredSum(acc);
  __shared__ float wsm[4];
  if ((threadIdx.x & 63) == 0) wsm[threadIdx.x >> 6] = acc;
  __syncthreads();
  if (threadIdx.x == 0) out[1 + pb] = (wsm[0] + wsm[1] + wsm[2] + wsm[3]) * (1.0f / NPT);
}

__global__ void loss_total(float* __restrict__ out) {
  int t = threadIdx.x;
  float x = (t < NPAIR) ? out[1 + t] : 0.f;
  x = wredSum(x);
  if (t == 0) out[0] = x / (float)NPAIR;
}

extern "C" void kernel_launch(void* const* d_in, const int* in_sizes, int n_in,
                              void* d_out, int out_size, void* d_ws, size_t ws_size,
                              hipStream_t stream) {
  const float* feat = (const float*)d_in[0];
  const int* sg = (const int*)d_in[1];
  float* out = (float*)d_out;
  char* ws = (char*)d_ws;

  size_t o = 0;
  __half* Cxy = (__half*)(ws + o); o += (size_t)NPAIR * NPT * NPT * 2;  // 58.7 MB
  __half* Cxx = (__half*)(ws + o); o += (size_t)NSG * NPT * NPT * 2;   // 16.8 MB
  float* G  = (float*)(ws + o); o += (size_t)NROW * DIM * 4;           // 8.4 MB
  float* sq = (float*)(ws + o); o += (size_t)NROW * 4;
  int* idx  = (int*)(ws + o); o += (size_t)NROW * 4;
  int* cnt  = (int*)(ws + o); o += 1024;
  float* f[2]; float* s[2]; float2* part[2];
  f[0] = (float*)(ws + o); o += (size_t)NPAIR * NPT * 4;
  s[0] = (float*)(ws + o); o += (size_t)NSG * NPT * 4;
  f[1] = (float*)(ws + o); o += (size_t)NPAIR * NPT * 4;
  s[1] = (float*)(ws + o); o += (size_t)NSG * NPT * 4;
  part[0] = (float2*)(ws + o); o += (size_t)NPAIR * NCH * NPT * 8;     // 3.7 MB
  part[1] = (float2*)(ws + o); o += (size_t)NPAIR * NCH * NPT * 8;

  hipMemsetAsync(cnt, 0, 1024, stream);
  hipMemsetAsync(f[0], 0, (size_t)(NPAIR + NSG) * NPT * 4, stream);  // f0, s0 contiguous
  part_init<<<NPAIR * NCH * NPT / 256, 256, 0, stream>>>(part[0]);

  build_idx<<<NROW / 256, 256, 0, stream>>>(sg, idx, cnt);
  gather_rows<<<NROW, 256, 0, stream>>>(feat, idx, G, sq);
  cost_gemm<<<NBLK * 64, 256, 0, stream>>>(G, sq, Cxy, Cxx);

  // epsilon schedule (mirrors reference trace-time logic)
  float sched[256];
  int ns = 0;
  {
    double e = 256.0;
    const double ratio = 0.9 * 0.9;
    const double tgt = 1e-4 * 1e-4;
    while (e > tgt) { sched[ns++] = (float)e; e *= ratio; }
    sched[ns++] = (float)tgt;
  }
  const float epsT = sched[ns - 1];

  int cur = 0;
  for (int k = 0; k < ns; k++) {
    sink_fused<<<FBLK + SBLK, 256, 0, stream>>>(Cxy, Cxx, f[cur], s[cur], part[cur],
                                                f[1 - cur], s[1 - cur], part[1 - cur],
                                                k ? sched[k - 1] : sched[0], sched[k], 0.5f, 0.5f);
    cur ^= 1;
  }
  // final extrapolation at eps_target (s not blended)
  sink_fused<<<FBLK + SBLK, 256, 0, stream>>>(Cxy, Cxx, f[cur], s[cur], part[cur],
                                              f[1 - cur], s[1 - cur], part[1 - cur],
                                              sched[ns - 1], epsT, 0.0f, 1.0f);
  cur ^= 1;
  loss_pairs<<<NPAIR, 256, 0, stream>>>(f[cur], s[cur], part[cur], out, epsT);
  loss_total<<<1, 64, 0, stream>>>(out);
}

// Round 3
// 4192.842 us; speedup vs baseline: 1.2449x; 1.0537x over previous
//
#include <hip/hip_runtime.h>
#include <hip/hip_fp16.h>
#include <cstddef>
#include <cstdint>

#define NSG   8
#define NPAIR 28
#define NBLK  36
#define NPT   1024
#define DIM   256
#define NROW  8192
#define NCH   16                 // 64-row chunks per 1024x1024 block
#define FBLK  (NPAIR * NCH)      // 448 f/g blocks
#define SBLK  (NSG * NCH)        // 128 s blocks
#define LOG_N 6.9314718055994531f

// triu_indices(8,1) pairs, then 8 self pairs
__constant__ int c_pa[NBLK] = {0,0,0,0,0,0,0,1,1,1,1,1,1,2,2,2,2,2,3,3,3,3,4,4,4,5,5,6, 0,1,2,3,4,5,6,7};
__constant__ int c_pb[NBLK] = {1,2,3,4,5,6,7,2,3,4,5,6,7,3,4,5,6,7,4,5,6,7,5,6,7,6,7,7, 0,1,2,3,4,5,6,7};

__device__ __forceinline__ float wredMax(float v) {
#pragma unroll
  for (int o = 32; o > 0; o >>= 1) v = fmaxf(v, __shfl_xor(v, o, 64));
  return v;
}
__device__ __forceinline__ float wredSum(float v) {
#pragma unroll
  for (int o = 32; o > 0; o >>= 1) v += __shfl_xor(v, o, 64);
  return v;
}

__device__ __forceinline__ float4 ld4h(const __half* pp) {
  union { uint2 u; __half2 h[2]; } t;
  t.u = *(const uint2*)pp;
  float2 lo = __half22float2(t.h[0]);
  float2 hi = __half22float2(t.h[1]);
  return make_float4(lo.x, lo.y, hi.x, hi.y);
}

// ---- phase 0: grouping ----
__global__ void build_idx(const int* __restrict__ sg, int* __restrict__ idx, int* __restrict__ cnt) {
  int i = blockIdx.x * 256 + threadIdx.x;
  if (i >= NROW) return;
  int s = sg[i];
  int r = atomicAdd(&cnt[s], 1);
  idx[s * NPT + r] = i;
}

__global__ void gather_rows(const float* __restrict__ feat, const int* __restrict__ idx,
                            float* __restrict__ G, float* __restrict__ sq) {
  int row = blockIdx.x;
  int src = idx[row];
  float v = feat[(size_t)src * DIM + threadIdx.x];
  G[(size_t)row * DIM + threadIdx.x] = v;
  float p = wredSum(v * v);
  __shared__ float ws[4];
  if ((threadIdx.x & 63) == 0) ws[threadIdx.x >> 6] = p;
  __syncthreads();
  if (threadIdx.x == 0) sq[row] = 0.5f * (ws[0] + ws[1] + ws[2] + ws[3]);
}

// ---- phase 1: cost matrices (fp16 output). 36 blocks of 1024x1024, tile 128x128 ----
__global__ __launch_bounds__(256) void cost_gemm(const float* __restrict__ G,
                                                 const float* __restrict__ sq,
                                                 __half* __restrict__ Cxy,
                                                 __half* __restrict__ Cxx) {
  __shared__ float As[8][128];
  __shared__ float Bt[8][128];
  int blk = blockIdx.x;
  int b = blk >> 6, t = blk & 63;
  int sa = c_pa[b], sb = c_pb[b];
  int i0 = (t >> 3) << 7, j0 = (t & 7) << 7;
  const float* Arows = G + (size_t)(sa * NPT + i0) * DIM;
  const float* Brows = G + (size_t)(sb * NPT + j0) * DIM;
  int tid = threadIdx.x;
  int ty = tid >> 4, tx = tid & 15;
  float acc[8][8];
#pragma unroll
  for (int r = 0; r < 8; r++)
#pragma unroll
    for (int q = 0; q < 8; q++) acc[r][q] = 0.f;

  int lrow = tid >> 1, lk4 = (tid & 1) << 2;
  for (int k0 = 0; k0 < DIM; k0 += 8) {
    __syncthreads();
    float4 av = *(const float4*)(Arows + (size_t)lrow * DIM + k0 + lk4);
    float4 bv = *(const float4*)(Brows + (size_t)lrow * DIM + k0 + lk4);
    As[lk4 + 0][lrow] = av.x; As[lk4 + 1][lrow] = av.y; As[lk4 + 2][lrow] = av.z; As[lk4 + 3][lrow] = av.w;
    Bt[lk4 + 0][lrow] = bv.x; Bt[lk4 + 1][lrow] = bv.y; Bt[lk4 + 2][lrow] = bv.z; Bt[lk4 + 3][lrow] = bv.w;
    __syncthreads();
#pragma unroll
    for (int kk = 0; kk < 8; kk++) {
      float4 a0 = *(const float4*)&As[kk][ty << 3];
      float4 a1 = *(const float4*)&As[kk][(ty << 3) + 4];
      float4 b0 = *(const float4*)&Bt[kk][tx << 3];
      float4 b1 = *(const float4*)&Bt[kk][(tx << 3) + 4];
      float ar[8] = {a0.x, a0.y, a0.z, a0.w, a1.x, a1.y, a1.z, a1.w};
      float br[8] = {b0.x, b0.y, b0.z, b0.w, b1.x, b1.y, b1.z, b1.w};
#pragma unroll
      for (int r = 0; r < 8; r++)
#pragma unroll
        for (int q = 0; q < 8; q++) acc[r][q] = fmaf(ar[r], br[q], acc[r][q]);
    }
  }
  __half* dst = (b < NPAIR) ? (Cxy + ((size_t)b << 20)) : (Cxx + ((size_t)(b - NPAIR) << 20));
  float sqa[8], sqb[8];
#pragma unroll
  for (int r = 0; r < 8; r++) sqa[r] = sq[sa * NPT + i0 + (ty << 3) + r];
#pragma unroll
  for (int q = 0; q < 8; q++) sqb[q] = sq[sb * NPT + j0 + (tx << 3) + q];
#pragma unroll
  for (int r = 0; r < 8; r++) {
    __half* drow = dst + (size_t)(i0 + (ty << 3) + r) * NPT + j0 + (tx << 3);
    union { float4 f4; __half h[8]; } o;
#pragma unroll
    for (int q = 0; q < 8; q++)
      o.h[q] = __float2half_rn(fmaxf(sqa[r] + sqb[q] - acc[r][q], 0.f));
    *(float4*)drow = o.f4;
  }
}

// ---- combine per-chunk column partials into the g vector (one thread per (p,j)) ----
__global__ void combine_g(const float2* __restrict__ part, float* __restrict__ g, float eps) {
  int jg = blockIdx.x * 256 + threadIdx.x;  // 28*1024 total
  int p = jg >> 10, j = jg & 1023;
  float ie = 1.0f / eps;
  const float2* pp = part + ((size_t)p << 14);
  float m = -3.4e38f, l = 0.f;
#pragma unroll
  for (int c = 0; c < NCH; c++) {
    float2 v = pp[(c << 10) + j];
    float nm = fmaxf(m, v.x);
    l = l * __expf((m - nm) * ie) + v.y * __expf((v.x - nm) * ie);
    m = nm;
  }
  g[jg] = -(m + eps * (__logf(l) - LOG_N));
}

// part_0 encodes g=0 for any eps: m=0, l = n/NCH
__global__ void part_init(float2* __restrict__ part) {
  int i = blockIdx.x * 256 + threadIdx.x;
  part[i] = make_float2(0.f, (float)(NPT / NCH));
}

// ---- phase 2: one fused Sinkhorn step (register-prefetch + LDS double buffer) ----
__global__ __launch_bounds__(256) void sink_fused(
    const __half* __restrict__ Cxy, const __half* __restrict__ Cxx,
    const float* __restrict__ f_cur, const float* __restrict__ s_cur,
    const float* __restrict__ gvec,
    float* __restrict__ f_nxt, float* __restrict__ s_nxt,
    float2* __restrict__ part_nxt,
    float eps, float csS, float cmS) {
  __shared__ __align__(16) __half tile[2][8][NPT];  // 2 x 16 KB
  __shared__ __align__(16) float hvec[NPT];
  __shared__ float fv[64];
  const int tid = threadIdx.x;
  const int b = blockIdx.x;
  const bool isF = (b < FBLK);
  const float ie = 1.0f / eps;
  int p, chunk;
  const __half* Cbase;
  if (isF) {
    p = b >> 4; chunk = b & 15;
    Cbase = Cxy + ((size_t)p << 20) + ((size_t)(chunk << 6) << 10);
  } else {
    const int bb = b - FBLK;
    p = bb >> 4; chunk = bb & 15;
    Cbase = Cxx + ((size_t)p << 20) + ((size_t)(chunk << 6) << 10);
  }

  // prologue: issue stage-0 C loads, then h/f loads, then stage into LDS buf 0
  const float4* gs0 = (const float4*)Cbase;
  float4 r0 = gs0[tid], r1 = gs0[tid + 256], r2 = gs0[tid + 512], r3 = gs0[tid + 768];
  if (isF) {
    float4 gv = ((const float4*)(gvec + p * NPT))[tid];
    *(float4*)&hvec[tid << 2] = gv;
    if (tid < 64) fv[tid] = f_cur[p * NPT + (chunk << 6) + tid];
  } else {
    float4 sv = ((const float4*)(s_cur + p * NPT))[tid];
    *(float4*)&hvec[tid << 2] = sv;
  }
  {
    float4* l0 = (float4*)&tile[0][0][0];
    l0[tid] = r0; l0[tid + 256] = r1; l0[tid + 512] = r2; l0[tid + 768] = r3;
  }
  __syncthreads();

  const int wave = tid >> 6, lane = tid & 63;
  float CM[4], CL[4];
#pragma unroll
  for (int q = 0; q < 4; q++) { CM[q] = -3.4e38f; CL[q] = 0.f; }

  for (int st = 0; st < 8; st++) {
    // prefetch next stage into registers (overlaps with compute below)
    if (st < 7) {
      const float4* gs = (const float4*)(Cbase + ((size_t)(st + 1) << 13));
      r0 = gs[tid]; r1 = gs[tid + 256]; r2 = gs[tid + 512]; r3 = gs[tid + 768];
    }
    const __half (*buf)[NPT] = tile[st & 1];

    // row phase: wave w handles rows w and w+4
#pragma unroll
    for (int rr = 0; rr < 2; rr++) {
      const int row = wave + (rr << 2);
      float a[16];
      float m = -3.4e38f;
#pragma unroll
      for (int c = 0; c < 4; c++) {
        const int col = (c << 8) + (lane << 2);
        float4 cv = ld4h(&buf[row][col]);
        float4 hv = *(const float4*)&hvec[col];
        a[4 * c + 0] = hv.x - cv.x; a[4 * c + 1] = hv.y - cv.y;
        a[4 * c + 2] = hv.z - cv.z; a[4 * c + 3] = hv.w - cv.w;
        m = fmaxf(m, fmaxf(fmaxf(a[4 * c + 0], a[4 * c + 1]), fmaxf(a[4 * c + 2], a[4 * c + 3])));
      }
      m = wredMax(m);
      float ssum = 0.f;
#pragma unroll
      for (int i = 0; i < 16; i++) ssum += __expf((a[i] - m) * ie);
      ssum = wredSum(ssum);
      if (lane == 0) {
        const float sm = -(m + eps * (__logf(ssum) - LOG_N));
        const int gr = (chunk << 6) + (st << 3) + row;
        if (isF) f_nxt[p * NPT + gr] = sm;
        else s_nxt[p * NPT + gr] = csS * hvec[gr] + cmS * sm;
      }
    }

    // col phase (f blocks only): thread owns 4 consecutive cols
    if (isF) {
      const int j4 = tid << 2;
      float av[4][8];
#pragma unroll
      for (int r = 0; r < 8; r++) {
        float4 cv = ld4h(&buf[r][j4]);
        const float fr = fv[(st << 3) + r];
        av[0][r] = fr - cv.x; av[1][r] = fr - cv.y;
        av[2][r] = fr - cv.z; av[3][r] = fr - cv.w;
      }
#pragma unroll
      for (int q = 0; q < 4; q++) {
        float cmx = av[q][0];
#pragma unroll
        for (int r = 1; r < 8; r++) cmx = fmaxf(cmx, av[q][r]);
        const float nm = fmaxf(CM[q], cmx);
        float l = CL[q] * __expf((CM[q] - nm) * ie);
#pragma unroll
        for (int r = 0; r < 8; r++) l += __expf((av[q][r] - nm) * ie);
        CM[q] = nm; CL[q] = l;
      }
    }

    // stage prefetched registers into the other LDS buffer
    if (st < 7) {
      float4* ld = (float4*)&tile[(st + 1) & 1][0][0];
      ld[tid] = r0; ld[tid + 256] = r1; ld[tid + 512] = r2; ld[tid + 768] = r3;
    }
    __syncthreads();
  }
  if (isF) {
    float2* pdst = part_nxt + ((size_t)(p << 4) + chunk) * NPT + (tid << 2);
#pragma unroll
    for (int q = 0; q < 4; q++) pdst[q] = make_float2(CM[q], CL[q]);
  }
}

// ---- phase 3: losses ----
__global__ void loss_pairs(const float* __restrict__ ff, const float* __restrict__ gf,
                           const float* __restrict__ sf, float* __restrict__ out) {
  int pb = blockIdx.x;
  int si = c_pa[pb], sj = c_pb[pb];
  float acc = 0.f;
  for (int t = threadIdx.x; t < NPT; t += 256)
    acc += (ff[pb * NPT + t] - sf[si * NPT + t]) + (gf[pb * NPT + t] - sf[sj * NPT + t]);
  acc = wredSum(acc);
  __shared__ float wsm[4];
  if ((threadIdx.x & 63) == 0) wsm[threadIdx.x >> 6] = acc;
  __syncthreads();
  if (threadIdx.x == 0) out[1 + pb] = (wsm[0] + wsm[1] + wsm[2] + wsm[3]) * (1.0f / NPT);
}

__global__ void loss_total(float* __restrict__ out) {
  int t = threadIdx.x;
  float x = (t < NPAIR) ? out[1 + t] : 0.f;
  x = wredSum(x);
  if (t == 0) out[0] = x / (float)NPAIR;
}

extern "C" void kernel_launch(void* const* d_in, const int* in_sizes, int n_in,
                              void* d_out, int out_size, void* d_ws, size_t ws_size,
                              hipStream_t stream) {
  const float* feat = (const float*)d_in[0];
  const int* sg = (const int*)d_in[1];
  float* out = (float*)d_out;
  char* ws = (char*)d_ws;

  size_t o = 0;
  __half* Cxy = (__half*)(ws + o); o += (size_t)NPAIR * NPT * NPT * 2;  // 58.7 MB
  __half* Cxx = (__half*)(ws + o); o += (size_t)NSG * NPT * NPT * 2;   // 16.8 MB
  float* G  = (float*)(ws + o); o += (size_t)NROW * DIM * 4;           // 8.4 MB
  float* sq = (float*)(ws + o); o += (size_t)NROW * 4;
  int* idx  = (int*)(ws + o); o += (size_t)NROW * 4;
  int* cnt  = (int*)(ws + o); o += 1024;
  float* f[2]; float* s[2]; float2* part[2];
  f[0] = (float*)(ws + o); o += (size_t)NPAIR * NPT * 4;
  s[0] = (float*)(ws + o); o += (size_t)NSG * NPT * 4;
  f[1] = (float*)(ws + o); o += (size_t)NPAIR * NPT * 4;
  s[1] = (float*)(ws + o); o += (size_t)NSG * NPT * 4;
  part[0] = (float2*)(ws + o); o += (size_t)NPAIR * NCH * NPT * 8;     // 3.7 MB
  part[1] = (float2*)(ws + o); o += (size_t)NPAIR * NCH * NPT * 8;
  float* gbuf = (float*)(ws + o); o += (size_t)NPAIR * NPT * 4;

  hipMemsetAsync(cnt, 0, 1024, stream);
  hipMemsetAsync(f[0], 0, (size_t)(NPAIR + NSG) * NPT * 4, stream);  // f0, s0 contiguous
  part_init<<<NPAIR * NCH * NPT / 256, 256, 0, stream>>>(part[0]);

  build_idx<<<NROW / 256, 256, 0, stream>>>(sg, idx, cnt);
  gather_rows<<<NROW, 256, 0, stream>>>(feat, idx, G, sq);
  cost_gemm<<<NBLK * 64, 256, 0, stream>>>(G, sq, Cxy, Cxx);

  // epsilon schedule (mirrors reference trace-time logic)
  float sched[256];
  int ns = 0;
  {
    double e = 256.0;
    const double ratio = 0.9 * 0.9;
    const double tgt = 1e-4 * 1e-4;
    while (e > tgt) { sched[ns++] = (float)e; e *= ratio; }
    sched[ns++] = (float)tgt;
  }
  const float epsT = sched[ns - 1];

  int cur = 0;
  for (int k = 0; k < ns; k++) {
    combine_g<<<NPAIR * NPT / 256, 256, 0, stream>>>(part[cur], gbuf, k ? sched[k - 1] : sched[0]);
    sink_fused<<<FBLK + SBLK, 256, 0, stream>>>(Cxy, Cxx, f[cur], s[cur], gbuf,
                                                f[1 - cur], s[1 - cur], part[1 - cur],
                                                sched[k], 0.5f, 0.5f);
    cur ^= 1;
  }
  // final extrapolation at eps_target (s not blended)
  combine_g<<<NPAIR * NPT / 256, 256, 0, stream>>>(part[cur], gbuf, sched[ns - 1]);
  sink_fused<<<FBLK + SBLK, 256, 0, stream>>>(Cxy, Cxx, f[cur], s[cur], gbuf,
                                              f[1 - cur], s[1 - cur], part[1 - cur],
                                              epsT, 0.0f, 1.0f);
  cur ^= 1;
  combine_g<<<NPAIR * NPT / 256, 256, 0, stream>>>(part[cur], gbuf, epsT);
  loss_pairs<<<NPAIR, 256, 0, stream>>>(f[cur], gbuf, s[cur], out);
  loss_total<<<1, 64, 0, stream>>>(out);
}

// Round 4
// 3824.393 us; speedup vs baseline: 1.3648x; 1.0963x over previous
//
#include <hip/hip_runtime.h>
#include <hip/hip_fp16.h>
#include <cstddef>
#include <cstdint>

#define NSG   8
#define NPAIR 28
#define NBLK  36
#define NPT   1024
#define DIM   256
#define NROW  8192
#define NCH   32                 // 32-row chunks per 1024x1024 block
#define FBLK  (NPAIR * NCH)      // 896 f/g blocks
#define SBLK  (NSG * NCH)        // 256 s blocks
#define LOG_N 6.9314718055994531f

// triu_indices(8,1) pairs, then 8 self pairs
__constant__ int c_pa[NBLK] = {0,0,0,0,0,0,0,1,1,1,1,1,1,2,2,2,2,2,3,3,3,3,4,4,4,5,5,6, 0,1,2,3,4,5,6,7};
__constant__ int c_pb[NBLK] = {1,2,3,4,5,6,7,2,3,4,5,6,7,3,4,5,6,7,4,5,6,7,5,6,7,6,7,7, 0,1,2,3,4,5,6,7};

__device__ __forceinline__ float wredMax(float v) {
#pragma unroll
  for (int o = 32; o > 0; o >>= 1) v = fmaxf(v, __shfl_xor(v, o, 64));
  return v;
}
__device__ __forceinline__ float wredSum(float v) {
#pragma unroll
  for (int o = 32; o > 0; o >>= 1) v += __shfl_xor(v, o, 64);
  return v;
}

__device__ __forceinline__ float4 ld4h(const __half* pp) {
  union { uint2 u; __half2 h[2]; } t;
  t.u = *(const uint2*)pp;
  float2 lo = __half22float2(t.h[0]);
  float2 hi = __half22float2(t.h[1]);
  return make_float4(lo.x, lo.y, hi.x, hi.y);
}

// ---- phase 0: grouping ----
__global__ void build_idx(const int* __restrict__ sg, int* __restrict__ idx, int* __restrict__ cnt) {
  int i = blockIdx.x * 256 + threadIdx.x;
  if (i >= NROW) return;
  int s = sg[i];
  int r = atomicAdd(&cnt[s], 1);
  idx[s * NPT + r] = i;
}

__global__ void gather_rows(const float* __restrict__ feat, const int* __restrict__ idx,
                            float* __restrict__ G, float* __restrict__ sq) {
  int row = blockIdx.x;
  int src = idx[row];
  float v = feat[(size_t)src * DIM + threadIdx.x];
  G[(size_t)row * DIM + threadIdx.x] = v;
  float p = wredSum(v * v);
  __shared__ float ws[4];
  if ((threadIdx.x & 63) == 0) ws[threadIdx.x >> 6] = p;
  __syncthreads();
  if (threadIdx.x == 0) sq[row] = 0.5f * (ws[0] + ws[1] + ws[2] + ws[3]);
}

// ---- phase 1: cost matrices (fp16 output). 36 blocks of 1024x1024, tile 128x128 ----
__global__ __launch_bounds__(256) void cost_gemm(const float* __restrict__ G,
                                                 const float* __restrict__ sq,
                                                 __half* __restrict__ Cxy,
                                                 __half* __restrict__ Cxx) {
  __shared__ float As[8][128];
  __shared__ float Bt[8][128];
  int blk = blockIdx.x;
  int b = blk >> 6, t = blk & 63;
  int sa = c_pa[b], sb = c_pb[b];
  int i0 = (t >> 3) << 7, j0 = (t & 7) << 7;
  const float* Arows = G + (size_t)(sa * NPT + i0) * DIM;
  const float* Brows = G + (size_t)(sb * NPT + j0) * DIM;
  int tid = threadIdx.x;
  int ty = tid >> 4, tx = tid & 15;
  float acc[8][8];
#pragma unroll
  for (int r = 0; r < 8; r++)
#pragma unroll
    for (int q = 0; q < 8; q++) acc[r][q] = 0.f;

  int lrow = tid >> 1, lk4 = (tid & 1) << 2;
  for (int k0 = 0; k0 < DIM; k0 += 8) {
    __syncthreads();
    float4 av = *(const float4*)(Arows + (size_t)lrow * DIM + k0 + lk4);
    float4 bv = *(const float4*)(Brows + (size_t)lrow * DIM + k0 + lk4);
    As[lk4 + 0][lrow] = av.x; As[lk4 + 1][lrow] = av.y; As[lk4 + 2][lrow] = av.z; As[lk4 + 3][lrow] = av.w;
    Bt[lk4 + 0][lrow] = bv.x; Bt[lk4 + 1][lrow] = bv.y; Bt[lk4 + 2][lrow] = bv.z; Bt[lk4 + 3][lrow] = bv.w;
    __syncthreads();
#pragma unroll
    for (int kk = 0; kk < 8; kk++) {
      float4 a0 = *(const float4*)&As[kk][ty << 3];
      float4 a1 = *(const float4*)&As[kk][(ty << 3) + 4];
      float4 b0 = *(const float4*)&Bt[kk][tx << 3];
      float4 b1 = *(const float4*)&Bt[kk][(tx << 3) + 4];
      float ar[8] = {a0.x, a0.y, a0.z, a0.w, a1.x, a1.y, a1.z, a1.w};
      float br[8] = {b0.x, b0.y, b0.z, b0.w, b1.x, b1.y, b1.z, b1.w};
#pragma unroll
      for (int r = 0; r < 8; r++)
#pragma unroll
        for (int q = 0; q < 8; q++) acc[r][q] = fmaf(ar[r], br[q], acc[r][q]);
    }
  }
  __half* dst = (b < NPAIR) ? (Cxy + ((size_t)b << 20)) : (Cxx + ((size_t)(b - NPAIR) << 20));
  float sqa[8], sqb[8];
#pragma unroll
  for (int r = 0; r < 8; r++) sqa[r] = sq[sa * NPT + i0 + (ty << 3) + r];
#pragma unroll
  for (int q = 0; q < 8; q++) sqb[q] = sq[sb * NPT + j0 + (tx << 3) + q];
#pragma unroll
  for (int r = 0; r < 8; r++) {
    __half* drow = dst + (size_t)(i0 + (ty << 3) + r) * NPT + j0 + (tx << 3);
    union { float4 f4; __half h[8]; } o;
#pragma unroll
    for (int q = 0; q < 8; q++)
      o.h[q] = __float2half_rn(fmaxf(sqa[r] + sqb[q] - acc[r][q], 0.f));
    *(float4*)drow = o.f4;
  }
}

// ---- combine per-chunk column partials into the g vector (one thread per (p,j)) ----
__global__ void combine_g(const float2* __restrict__ part, float* __restrict__ g, float eps) {
  int jg = blockIdx.x * 256 + threadIdx.x;  // 28*1024 total
  int p = jg >> 10, j = jg & 1023;
  float ie = 1.0f / eps;
  const float2* pp = part + ((size_t)p << 15);
  float m = -3.4e38f, l = 0.f;
#pragma unroll
  for (int c = 0; c < NCH; c++) {
    float2 v = pp[(c << 10) + j];
    float nm = fmaxf(m, v.x);
    l = l * __expf((m - nm) * ie) + v.y * __expf((v.x - nm) * ie);
    m = nm;
  }
  g[jg] = -(m + eps * (__logf(l) - LOG_N));
}

// part_0 encodes g=0 for any eps: m=0, l = n/NCH
__global__ void part_init(float2* __restrict__ part) {
  int i = blockIdx.x * 256 + threadIdx.x;
  part[i] = make_float2(0.f, (float)(NPT / NCH));
}

// ---- phase 2: one fused Sinkhorn step ----
// Single 16 KB LDS tile, register prefetch of the next 8-row stage, 4 stages/block.
__global__ __launch_bounds__(256) void sink_fused(
    const __half* __restrict__ Cxy, const __half* __restrict__ Cxx,
    const float* __restrict__ f_cur, const float* __restrict__ s_cur,
    const float* __restrict__ gvec,
    float* __restrict__ f_nxt, float* __restrict__ s_nxt,
    float2* __restrict__ part_nxt,
    float eps, float csS, float cmS) {
  __shared__ __align__(16) __half tile[8][NPT];   // 16 KB
  __shared__ __align__(16) float hvec[NPT];       // 4 KB
  __shared__ float fv[32];
  const int tid = threadIdx.x;
  const int b = blockIdx.x;
  const bool isF = (b < FBLK);
  const float ie = 1.0f / eps;
  int p, chunk;
  const __half* Cbase;
  if (isF) {
    p = b >> 5; chunk = b & 31;
    Cbase = Cxy + ((size_t)p << 20) + ((size_t)(chunk << 5) << 10);
  } else {
    const int bb = b - FBLK;
    p = bb >> 5; chunk = bb & 31;
    Cbase = Cxx + ((size_t)p << 20) + ((size_t)(chunk << 5) << 10);
  }

  // prologue: stage-0 loads, h/f loads, stage into LDS
  const float4* gs0 = (const float4*)Cbase;
  float4 r0 = gs0[tid], r1 = gs0[tid + 256], r2 = gs0[tid + 512], r3 = gs0[tid + 768];
  if (isF) {
    *(float4*)&hvec[tid << 2] = ((const float4*)(gvec + p * NPT))[tid];
    if (tid < 32) fv[tid] = f_cur[p * NPT + (chunk << 5) + tid];
  } else {
    *(float4*)&hvec[tid << 2] = ((const float4*)(s_cur + p * NPT))[tid];
  }
  {
    float4* l0 = (float4*)&tile[0][0];
    l0[tid] = r0; l0[tid + 256] = r1; l0[tid + 512] = r2; l0[tid + 768] = r3;
  }
  __syncthreads();

  const int wave = tid >> 6, lane = tid & 63;
  float CM[4], CL[4];
#pragma unroll
  for (int q = 0; q < 4; q++) { CM[q] = -3.4e38f; CL[q] = 0.f; }

  for (int st = 0; st < 4; st++) {
    // prefetch next stage into registers (overlaps with compute below)
    if (st < 3) {
      const float4* gs = (const float4*)(Cbase + ((size_t)(st + 1) << 13));
      r0 = gs[tid]; r1 = gs[tid + 256]; r2 = gs[tid + 512]; r3 = gs[tid + 768];
    }

    // row phase: wave w handles rows w and w+4
#pragma unroll
    for (int rr = 0; rr < 2; rr++) {
      const int row = wave + (rr << 2);
      float a[16];
      float m = -3.4e38f;
#pragma unroll
      for (int c = 0; c < 4; c++) {
        const int col = (c << 8) + (lane << 2);
        float4 cv = ld4h(&tile[row][col]);
        float4 hv = *(const float4*)&hvec[col];
        a[4 * c + 0] = hv.x - cv.x; a[4 * c + 1] = hv.y - cv.y;
        a[4 * c + 2] = hv.z - cv.z; a[4 * c + 3] = hv.w - cv.w;
        m = fmaxf(m, fmaxf(fmaxf(a[4 * c + 0], a[4 * c + 1]), fmaxf(a[4 * c + 2], a[4 * c + 3])));
      }
      m = wredMax(m);
      float ssum = 0.f;
#pragma unroll
      for (int i = 0; i < 16; i++) ssum += __expf((a[i] - m) * ie);
      ssum = wredSum(ssum);
      if (lane == 0) {
        const float sm = -(m + eps * (__logf(ssum) - LOG_N));
        const int gr = (chunk << 5) + (st << 3) + row;
        if (isF) f_nxt[p * NPT + gr] = sm;
        else s_nxt[p * NPT + gr] = csS * hvec[gr] + cmS * sm;
      }
    }

    // col phase (f blocks only): thread owns 4 consecutive cols
    if (isF) {
      const int j4 = tid << 2;
      float av[4][8];
#pragma unroll
      for (int r = 0; r < 8; r++) {
        float4 cv = ld4h(&tile[r][j4]);
        const float fr = fv[(st << 3) + r];
        av[0][r] = fr - cv.x; av[1][r] = fr - cv.y;
        av[2][r] = fr - cv.z; av[3][r] = fr - cv.w;
      }
#pragma unroll
      for (int q = 0; q < 4; q++) {
        float cmx = av[q][0];
#pragma unroll
        for (int r = 1; r < 8; r++) cmx = fmaxf(cmx, av[q][r]);
        const float nm = fmaxf(CM[q], cmx);
        float l = CL[q] * __expf((CM[q] - nm) * ie);
#pragma unroll
        for (int r = 0; r < 8; r++) l += __expf((av[q][r] - nm) * ie);
        CM[q] = nm; CL[q] = l;
      }
    }

    // store prefetched registers into the (single) LDS tile
    if (st < 3) {
      __syncthreads();
      float4* ld = (float4*)&tile[0][0];
      ld[tid] = r0; ld[tid + 256] = r1; ld[tid + 512] = r2; ld[tid + 768] = r3;
      __syncthreads();
    }
  }
  if (isF) {
    float2* pdst = part_nxt + ((size_t)(p << 5) + chunk) * NPT + (tid << 2);
#pragma unroll
    for (int q = 0; q < 4; q++) pdst[q] = make_float2(CM[q], CL[q]);
  }
}

// ---- phase 3: losses ----
__global__ void loss_pairs(const float* __restrict__ ff, const float* __restrict__ gf,
                           const float* __restrict__ sf, float* __restrict__ out) {
  int pb = blockIdx.x;
  int si = c_pa[pb], sj = c_pb[pb];
  float acc = 0.f;
  for (int t = threadIdx.x; t < NPT; t += 256)
    acc += (ff[pb * NPT + t] - sf[si * NPT + t]) + (gf[pb * NPT + t] - sf[sj * NPT + t]);
  acc = wredSum(acc);
  __shared__ float wsm[4];
  if ((threadIdx.x & 63) == 0) wsm[threadIdx.x >> 6] = acc;
  __syncthreads();
  if (threadIdx.x == 0) out[1 + pb] = (wsm[0] + wsm[1] + wsm[2] + wsm[3]) * (1.0f / NPT);
}

__global__ void loss_total(float* __restrict__ out) {
  int t = threadIdx.x;
  float x = (t < NPAIR) ? out[1 + t] : 0.f;
  x = wredSum(x);
  if (t == 0) out[0] = x / (float)NPAIR;
}

extern "C" void kernel_launch(void* const* d_in, const int* in_sizes, int n_in,
                              void* d_out, int out_size, void* d_ws, size_t ws_size,
                              hipStream_t stream) {
  const float* feat = (const float*)d_in[0];
  const int* sg = (const int*)d_in[1];
  float* out = (float*)d_out;
  char* ws = (char*)d_ws;

  size_t o = 0;
  __half* Cxy = (__half*)(ws + o); o += (size_t)NPAIR * NPT * NPT * 2;  // 58.7 MB
  __half* Cxx = (__half*)(ws + o); o += (size_t)NSG * NPT * NPT * 2;   // 16.8 MB
  float* G  = (float*)(ws + o); o += (size_t)NROW * DIM * 4;           // 8.4 MB
  float* sq = (float*)(ws + o); o += (size_t)NROW * 4;
  int* idx  = (int*)(ws + o); o += (size_t)NROW * 4;
  int* cnt  = (int*)(ws + o); o += 1024;
  float* f[2]; float* s[2]; float2* part[2];
  f[0] = (float*)(ws + o); o += (size_t)NPAIR * NPT * 4;
  s[0] = (float*)(ws + o); o += (size_t)NSG * NPT * 4;
  f[1] = (float*)(ws + o); o += (size_t)NPAIR * NPT * 4;
  s[1] = (float*)(ws + o); o += (size_t)NSG * NPT * 4;
  part[0] = (float2*)(ws + o); o += (size_t)NPAIR * NCH * NPT * 8;     // 7.3 MB
  part[1] = (float2*)(ws + o); o += (size_t)NPAIR * NCH * NPT * 8;
  float* gbuf = (float*)(ws + o); o += (size_t)NPAIR * NPT * 4;

  hipMemsetAsync(cnt, 0, 1024, stream);
  hipMemsetAsync(f[0], 0, (size_t)(NPAIR + NSG) * NPT * 4, stream);  // f0, s0 contiguous
  part_init<<<NPAIR * NCH * NPT / 256, 256, 0, stream>>>(part[0]);

  build_idx<<<NROW / 256, 256, 0, stream>>>(sg, idx, cnt);
  gather_rows<<<NROW, 256, 0, stream>>>(feat, idx, G, sq);
  cost_gemm<<<NBLK * 64, 256, 0, stream>>>(G, sq, Cxy, Cxx);

  // epsilon schedule (mirrors reference trace-time logic)
  float sched[256];
  int ns = 0;
  {
    double e = 256.0;
    const double ratio = 0.9 * 0.9;
    const double tgt = 1e-4 * 1e-4;
    while (e > tgt) { sched[ns++] = (float)e; e *= ratio; }
    sched[ns++] = (float)tgt;
  }
  const float epsT = sched[ns - 1];

  int cur = 0;
  for (int k = 0; k < ns; k++) {
    combine_g<<<NPAIR * NPT / 256, 256, 0, stream>>>(part[cur], gbuf, k ? sched[k - 1] : sched[0]);
    sink_fused<<<FBLK + SBLK, 256, 0, stream>>>(Cxy, Cxx, f[cur], s[cur], gbuf,
                                                f[1 - cur], s[1 - cur], part[1 - cur],
                                                sched[k], 0.5f, 0.5f);
    cur ^= 1;
  }
  // final extrapolation at eps_target (s not blended)
  combine_g<<<NPAIR * NPT / 256, 256, 0, stream>>>(part[cur], gbuf, sched[ns - 1]);
  sink_fused<<<FBLK + SBLK, 256, 0, stream>>>(Cxy, Cxx, f[cur], s[cur], gbuf,
                                              f[1 - cur], s[1 - cur], part[1 - cur],
                                              epsT, 0.0f, 1.0f);
  cur ^= 1;
  combine_g<<<NPAIR * NPT / 256, 256, 0, stream>>>(part[cur], gbuf, epsT);
  loss_pairs<<<NPAIR, 256, 0, stream>>>(f[cur], gbuf, s[cur], out);
  loss_total<<<1, 64, 0, stream>>>(out);
}

// Round 6
// 3682.634 us; speedup vs baseline: 1.4173x; 1.0385x over previous
//
#include <hip/hip_runtime.h>
#include <hip/hip_fp16.h>
#include <cstddef>
#include <cstdint>

#define NSG   8
#define NPAIR 28
#define NBLK  36
#define NMAT  64                 // ordered-pair matrices: q = 8a+b; diag = self costs
#define NPT   1024
#define DIM   256
#define NROW  8192
#define LOG_N  6.9314718055994531f
#define LOG2E  1.4426950408889634f

// triu_indices(8,1) pairs, then 8 self pairs
__constant__ int c_pa[NBLK] = {0,0,0,0,0,0,0,1,1,1,1,1,1,2,2,2,2,2,3,3,3,3,4,4,4,5,5,6, 0,1,2,3,4,5,6,7};
__constant__ int c_pb[NBLK] = {1,2,3,4,5,6,7,2,3,4,5,6,7,3,4,5,6,7,4,5,6,7,5,6,7,6,7,7, 0,1,2,3,4,5,6,7};

__device__ __forceinline__ float wredMax(float v) {
#pragma unroll
  for (int o = 32; o > 0; o >>= 1) v = fmaxf(v, __shfl_xor(v, o, 64));
  return v;
}
__device__ __forceinline__ float wredSum(float v) {
#pragma unroll
  for (int o = 32; o > 0; o >>= 1) v += __shfl_xor(v, o, 64);
  return v;
}

__device__ __forceinline__ float4 ld4h(const __half* pp) {
  union { uint2 u; __half2 h[2]; } t;
  t.u = *(const uint2*)pp;
  float2 lo = __half22float2(t.h[0]);
  float2 hi = __half22float2(t.h[1]);
  return make_float4(lo.x, lo.y, hi.x, hi.y);
}

// ---- phase 0: grouping ----
__global__ void build_idx(const int* __restrict__ sg, int* __restrict__ idx, int* __restrict__ cnt) {
  int i = blockIdx.x * 256 + threadIdx.x;
  if (i >= NROW) return;
  int s = sg[i];
  int r = atomicAdd(&cnt[s], 1);
  idx[s * NPT + r] = i;
}

__global__ void gather_rows(const float* __restrict__ feat, const int* __restrict__ idx,
                            float* __restrict__ G, float* __restrict__ sq) {
  int row = blockIdx.x;
  int src = idx[row];
  float v = feat[(size_t)src * DIM + threadIdx.x];
  G[(size_t)row * DIM + threadIdx.x] = v;
  float p = wredSum(v * v);
  __shared__ float ws[4];
  if ((threadIdx.x & 63) == 0) ws[threadIdx.x >> 6] = p;
  __syncthreads();
  if (threadIdx.x == 0) sq[row] = 0.5f * (ws[0] + ws[1] + ws[2] + ws[3]);
}

// ---- phase 1: cost matrices (fp16) into unified C[q=8a+b]; 36 unique products ----
__global__ __launch_bounds__(256) void cost_gemm(const float* __restrict__ G,
                                                 const float* __restrict__ sq,
                                                 __half* __restrict__ C) {
  __shared__ float As[8][128];
  __shared__ float Bt[8][128];
  int blk = blockIdx.x;
  int b = blk >> 6, t = blk & 63;
  int sa = c_pa[b], sb = c_pb[b];
  int i0 = (t >> 3) << 7, j0 = (t & 7) << 7;
  const float* Arows = G + (size_t)(sa * NPT + i0) * DIM;
  const float* Brows = G + (size_t)(sb * NPT + j0) * DIM;
  int tid = threadIdx.x;
  int ty = tid >> 4, tx = tid & 15;
  float acc[8][8];
#pragma unroll
  for (int r = 0; r < 8; r++)
#pragma unroll
    for (int q = 0; q < 8; q++) acc[r][q] = 0.f;

  int lrow = tid >> 1, lk4 = (tid & 1) << 2;
  for (int k0 = 0; k0 < DIM; k0 += 8) {
    __syncthreads();
    float4 av = *(const float4*)(Arows + (size_t)lrow * DIM + k0 + lk4);
    float4 bv = *(const float4*)(Brows + (size_t)lrow * DIM + k0 + lk4);
    As[lk4 + 0][lrow] = av.x; As[lk4 + 1][lrow] = av.y; As[lk4 + 2][lrow] = av.z; As[lk4 + 3][lrow] = av.w;
    Bt[lk4 + 0][lrow] = bv.x; Bt[lk4 + 1][lrow] = bv.y; Bt[lk4 + 2][lrow] = bv.z; Bt[lk4 + 3][lrow] = bv.w;
    __syncthreads();
#pragma unroll
    for (int kk = 0; kk < 8; kk++) {
      float4 a0 = *(const float4*)&As[kk][ty << 3];
      float4 a1 = *(const float4*)&As[kk][(ty << 3) + 4];
      float4 b0 = *(const float4*)&Bt[kk][tx << 3];
      float4 b1 = *(const float4*)&Bt[kk][(tx << 3) + 4];
      float ar[8] = {a0.x, a0.y, a0.z, a0.w, a1.x, a1.y, a1.z, a1.w};
      float br[8] = {b0.x, b0.y, b0.z, b0.w, b1.x, b1.y, b1.z, b1.w};
#pragma unroll
      for (int r = 0; r < 8; r++)
#pragma unroll
        for (int q = 0; q < 8; q++) acc[r][q] = fmaf(ar[r], br[q], acc[r][q]);
    }
  }
  int qd = 8 * sa + sb;   // diag for b>=28 since sa==sb there
  __half* dst = C + ((size_t)qd << 20);
  float sqa[8], sqb[8];
#pragma unroll
  for (int r = 0; r < 8; r++) sqa[r] = sq[sa * NPT + i0 + (ty << 3) + r];
#pragma unroll
  for (int q = 0; q < 8; q++) sqb[q] = sq[sb * NPT + j0 + (tx << 3) + q];
#pragma unroll
  for (int r = 0; r < 8; r++) {
    __half* drow = dst + (size_t)(i0 + (ty << 3) + r) * NPT + j0 + (tx << 3);
    union { float4 f4; __half h[8]; } o;
#pragma unroll
    for (int q = 0; q < 8; q++)
      o.h[q] = __float2half_rn(fmaxf(sqa[r] + sqb[q] - acc[r][q], 0.f));
    *(float4*)drow = o.f4;
  }
}

// ---- phase 1b: fill mate slots C[8b+a] = C[8a+b]^T for the 28 cross pairs ----
__global__ __launch_bounds__(256) void transpose_c(__half* __restrict__ C) {
  __shared__ __half t[64][72];   // pad to 72 halfs
  int b = blockIdx.x;            // p*256 + tile
  int p = b >> 8;
  int tb = b & 255;
  int i0 = (tb >> 4) << 6, j0 = (tb & 15) << 6;
  int qs = 8 * c_pa[p] + c_pb[p];
  int qd = 8 * c_pb[p] + c_pa[p];
  const __half* src = C + ((size_t)qs << 20);
  __half* dst = C + ((size_t)qd << 20);
  int tid = threadIdx.x;
  int r = tid >> 2, cg = (tid & 3) << 4;
  const float4* s4 = (const float4*)(src + ((size_t)(i0 + r) << 10) + j0 + cg);
  float4 v0 = s4[0], v1 = s4[1];
  *(float4*)&t[r][cg] = v0;
  *(float4*)&t[r][cg + 8] = v1;
  __syncthreads();
  union { float4 f4[2]; __half h[16]; } o;
#pragma unroll
  for (int k = 0; k < 16; k++) o.h[k] = t[cg + k][r];
  float4* d4 = (float4*)(dst + ((size_t)(j0 + r) << 10) + i0 + cg);
  d4[0] = o.f4[0];
  d4[1] = o.f4[1];
}

// ---- phase 2: one Sinkhorn step = 64 row-softmins. LDS-free streaming kernel. ----
__global__ __launch_bounds__(256) void sink_step(
    const __half* __restrict__ C, const float* __restrict__ pot_cur,
    float* __restrict__ pot_nxt, float eps, float csS, float cmS) {
  const int b = blockIdx.x;
  const int q = b >> 5, chunk = b & 31;
  const int mate = ((q & 7) << 3) | (q >> 3);
  const bool diag = (mate == q);
  const float cs = diag ? csS : 0.f;
  const float cm = diag ? cmS : 1.f;
  const int wave = threadIdx.x >> 6, lane = threadIdx.x & 63;
  const float* hp = pot_cur + (mate << 10) + (lane << 2);
  const float4 h0 = *(const float4*)(hp);
  const float4 h1 = *(const float4*)(hp + 256);
  const float4 h2 = *(const float4*)(hp + 512);
  const float4 h3 = *(const float4*)(hp + 768);
  const float c0 = LOG2E / eps;
  const __half* Cb = C + ((size_t)q << 20) + ((size_t)(chunk << 5) << 10);

  for (int k = 0; k < 8; k++) {
    const int lr = (k << 2) + wave;
    const __half* Crow = Cb + ((size_t)lr << 10) + (lane << 2);
    float4 v0 = ld4h(Crow);
    float4 v1 = ld4h(Crow + 256);
    float4 v2 = ld4h(Crow + 512);
    float4 v3 = ld4h(Crow + 768);
    float a[16];
    a[0]  = h0.x - v0.x; a[1]  = h0.y - v0.y; a[2]  = h0.z - v0.z; a[3]  = h0.w - v0.w;
    a[4]  = h1.x - v1.x; a[5]  = h1.y - v1.y; a[6]  = h1.z - v1.z; a[7]  = h1.w - v1.w;
    a[8]  = h2.x - v2.x; a[9]  = h2.y - v2.y; a[10] = h2.z - v2.z; a[11] = h2.w - v2.w;
    a[12] = h3.x - v3.x; a[13] = h3.y - v3.y; a[14] = h3.z - v3.z; a[15] = h3.w - v3.w;
    float m = a[0];
#pragma unroll
    for (int i = 1; i < 16; i++) m = fmaxf(m, a[i]);
    m = wredMax(m);
    // NOTE: subtract BEFORE scaling. (a-m) is exact for the max lane; scaling a
    // pre-rounded m*c0 (fmaf residual ~ulp(m*c0) ~ 4096 at eps=1e-8) overflows exp2.
    float ssum = 0.f;
#pragma unroll
    for (int i = 0; i < 16; i++) ssum += exp2f((a[i] - m) * c0);
    ssum = wredSum(ssum);
    if (lane == 0) {
      const float sm = -(m + eps * (__logf(ssum) - LOG_N));
      const int gr = (chunk << 5) + lr;
      pot_nxt[(q << 10) + gr] = cs * pot_cur[(q << 10) + gr] + cm * sm;
    }
  }
}

// ---- phase 3: losses ----
__global__ void loss_pairs(const float* __restrict__ pot, float* __restrict__ out) {
  int pb = blockIdx.x;
  int si = c_pa[pb], sj = c_pb[pb];
  const float* fv = pot + ((8 * si + sj) << 10);
  const float* gv = pot + ((8 * sj + si) << 10);
  const float* sa = pot + ((9 * si) << 10);
  const float* sb = pot + ((9 * sj) << 10);
  float acc = 0.f;
  for (int t = threadIdx.x; t < NPT; t += 256)
    acc += (fv[t] - sa[t]) + (gv[t] - sb[t]);
  acc = wredSum(acc);
  __shared__ float wsm[4];
  if ((threadIdx.x & 63) == 0) wsm[threadIdx.x >> 6] = acc;
  __syncthreads();
  if (threadIdx.x == 0) out[1 + pb] = (wsm[0] + wsm[1] + wsm[2] + wsm[3]) * (1.0f / NPT);
}

__global__ void loss_total(float* __restrict__ out) {
  int t = threadIdx.x;
  float x = (t < NPAIR) ? out[1 + t] : 0.f;
  x = wredSum(x);
  if (t == 0) out[0] = x / (float)NPAIR;
}

extern "C" void kernel_launch(void* const* d_in, const int* in_sizes, int n_in,
                              void* d_out, int out_size, void* d_ws, size_t ws_size,
                              hipStream_t stream) {
  const float* feat = (const float*)d_in[0];
  const int* sg = (const int*)d_in[1];
  float* out = (float*)d_out;
  char* ws = (char*)d_ws;

  size_t o = 0;
  __half* C = (__half*)(ws + o); o += (size_t)NMAT * NPT * NPT * 2;   // 128 MB
  float* G  = (float*)(ws + o); o += (size_t)NROW * DIM * 4;          // 8.4 MB
  float* sq = (float*)(ws + o); o += (size_t)NROW * 4;
  int* idx  = (int*)(ws + o); o += (size_t)NROW * 4;
  int* cnt  = (int*)(ws + o); o += 1024;
  float* pot[2];
  pot[0] = (float*)(ws + o); o += (size_t)NMAT * NPT * 4;             // 256 KB
  pot[1] = (float*)(ws + o); o += (size_t)NMAT * NPT * 4;

  hipMemsetAsync(cnt, 0, 1024, stream);
  hipMemsetAsync(pot[0], 0, (size_t)NMAT * NPT * 4, stream);   // f0=g0=s0=0

  build_idx<<<NROW / 256, 256, 0, stream>>>(sg, idx, cnt);
  gather_rows<<<NROW, 256, 0, stream>>>(feat, idx, G, sq);
  cost_gemm<<<NBLK * 64, 256, 0, stream>>>(G, sq, C);
  transpose_c<<<NPAIR * 256, 256, 0, stream>>>(C);

  // epsilon schedule (mirrors reference trace-time logic)
  float sched[256];
  int ns = 0;
  {
    double e = 256.0;
    const double ratio = 0.9 * 0.9;
    const double tgt = 1e-4 * 1e-4;
    while (e > tgt) { sched[ns++] = (float)e; e *= ratio; }
    sched[ns++] = (float)tgt;
  }
  const float epsT = sched[ns - 1];

  int cur = 0;
  for (int k = 0; k < ns; k++) {
    sink_step<<<NMAT * 32, 256, 0, stream>>>(C, pot[cur], pot[1 - cur], sched[k], 0.5f, 0.5f);
    cur ^= 1;
  }
  // final extrapolation at eps_target (diag not blended)
  sink_step<<<NMAT * 32, 256, 0, stream>>>(C, pot[cur], pot[1 - cur], epsT, 0.0f, 1.0f);
  cur ^= 1;
  loss_pairs<<<NPAIR, 256, 0, stream>>>(pot[cur], out);
  loss_total<<<1, 64, 0, stream>>>(out);
}